// Round 1
// baseline (199.435 us; speedup 1.0000x reference)
//
#include <hip/hip_runtime.h>

typedef unsigned short u16;

typedef __bf16 bf16x8_ __attribute__((ext_vector_type(8)));
typedef float f32x4 __attribute__((ext_vector_type(4)));
typedef float f32x4__ __attribute__((ext_vector_type(4)));
typedef unsigned int u32x4_ __attribute__((ext_vector_type(4)));
typedef unsigned int u32x2_ __attribute__((ext_vector_type(2)));

typedef bf16x8_ __attribute__((may_alias)) bf16x8;
typedef u32x4_ __attribute__((may_alias)) u32x4;
typedef u32x2_ __attribute__((may_alias)) u32x2;
typedef f32x4__ __attribute__((may_alias)) f32x4a;

#define MFMA16(a, b, c) __builtin_amdgcn_mfma_f32_16x16x32_bf16(a, b, c, 0, 0, 0)

#define BN 2048
#define CDIM 768
#define HEADS 12
#define HD 64
#define NBH 24
#define MROWS 4096

__device__ __forceinline__ u16 f2bf(float f) {
    unsigned u = __float_as_uint(f);
    u += 0x7fffu + ((u >> 16) & 1u);
    return (u16)(u >> 16);
}

// ---------------- cast x (fp32 -> bf16), 8 elems/thread ----------------
__global__ void cast_x_kernel(const float* __restrict__ in, u16* __restrict__ out, int n8) {
    int i = blockIdx.x * 256 + threadIdx.x;
    if (i >= n8) return;
    const f32x4a* p = (const f32x4a*)in;
    f32x4a a = p[2 * (size_t)i], b = p[2 * (size_t)i + 1];
    union { u16 h[8]; u32x4_ v; } o;
#pragma unroll
    for (int j = 0; j < 4; ++j) { o.h[j] = f2bf(a[j]); o.h[4 + j] = f2bf(b[j]); }
    *(u32x4*)(out + (size_t)8 * i) = o.v;
}

// ---------------- tiled transpose (-> bf16). in [R][C] -> out [C][R] ----------------
template <typename T>
__global__ void transpose_to_bf16(const T* __restrict__ in, u16* __restrict__ out,
                                  int R, int C, long long ib, long long ob) {
    __shared__ u16 tile[64][66];
    const T* pin = in + (size_t)blockIdx.z * ib;
    u16* pout = out + (size_t)blockIdx.z * ob;
    int r0 = blockIdx.y * 64, c0 = blockIdx.x * 64;
    int tid = threadIdx.x;
#pragma unroll
    for (int i = 0; i < 16; ++i) {
        int idx = tid + i * 256;
        int r = idx >> 6, c = idx & 63;
        T v = pin[(size_t)(r0 + r) * C + c0 + c];
        if constexpr (sizeof(T) == 4) tile[r][c] = f2bf((float)v);
        else                          tile[r][c] = (u16)v;
    }
    __syncthreads();
#pragma unroll
    for (int i = 0; i < 16; ++i) {
        int idx = tid + i * 256;
        int c = idx >> 6, r = idx & 63;
        pout[(size_t)(c0 + c) * R + r0 + r] = tile[r][c];
    }
}

// ---------------- GEMM: C[M,N] = A[M,K] * Bt[N,K]^T + bias ----------------
// 128x128 tile, BK=64, 4 waves (2x2), 16x16x32 bf16 MFMA, swizzled LDS.
// EPI 0: scatter to Q(x0.125)/K/V buffers [BH][N][D] bf16.  EPI 1: fp32 out.
template <int EPI>
__global__ __launch_bounds__(256) void gemm_bt(
    const u16* __restrict__ A, const u16* __restrict__ Bt,
    const float* __restrict__ bias, int M, int N, int K,
    u16* __restrict__ Qb, u16* __restrict__ Kb, u16* __restrict__ Vb,
    float* __restrict__ Out) {
    __shared__ u16 As[128 * 64];
    __shared__ u16 Bs[128 * 64];
    int tid = threadIdx.x;
    int wid = tid >> 6, lane = tid & 63, lr = lane & 15, lhi = lane >> 4;
    int wr = wid >> 1, wc = wid & 1;
    int m0 = blockIdx.x * 128, n0 = blockIdx.y * 128;

    f32x4 acc[4][4];
#pragma unroll
    for (int i = 0; i < 4; ++i)
#pragma unroll
        for (int j = 0; j < 4; ++j) acc[i][j] = f32x4{0.f, 0.f, 0.f, 0.f};

    for (int k0 = 0; k0 < K; k0 += 64) {
#pragma unroll
        for (int it = 0; it < 4; ++it) {
            int idx = tid + it * 256;
            int row = idx >> 3, ch = idx & 7;
            u32x4 av = *(const u32x4*)(A + (size_t)(m0 + row) * K + k0 + ch * 8);
            *(u32x4*)(As + row * 64 + ((ch ^ (row & 7)) * 8)) = av;
            u32x4 bv = *(const u32x4*)(Bt + (size_t)(n0 + row) * K + k0 + ch * 8);
            *(u32x4*)(Bs + row * 64 + ((ch ^ (row & 7)) * 8)) = bv;
        }
        __syncthreads();

        bf16x8 af[2][4], bfr[2][4];
#pragma unroll
        for (int x = 0; x < 4; ++x) {
            int ra = wr * 64 + x * 16 + lr;
            af[0][x] = *(const bf16x8*)(As + ra * 64 + ((lhi ^ (ra & 7)) * 8));
            af[1][x] = *(const bf16x8*)(As + ra * 64 + (((4 + lhi) ^ (ra & 7)) * 8));
            int rb = wc * 64 + x * 16 + lr;
            bfr[0][x] = *(const bf16x8*)(Bs + rb * 64 + ((lhi ^ (rb & 7)) * 8));
            bfr[1][x] = *(const bf16x8*)(Bs + rb * 64 + (((4 + lhi) ^ (rb & 7)) * 8));
        }
#pragma unroll
        for (int kc = 0; kc < 2; ++kc)
#pragma unroll
            for (int mi = 0; mi < 4; ++mi)
#pragma unroll
                for (int ni = 0; ni < 4; ++ni)
                    acc[mi][ni] = MFMA16(af[kc][mi], bfr[kc][ni], acc[mi][ni]);
        __syncthreads();
    }

#pragma unroll
    for (int mi = 0; mi < 4; ++mi) {
#pragma unroll
        for (int ni = 0; ni < 4; ++ni) {
            int col = n0 + wc * 64 + ni * 16 + lr;
            float bv = bias[col];
#pragma unroll
            for (int j = 0; j < 4; ++j) {
                int row = m0 + wr * 64 + mi * 16 + lhi * 4 + j;
                float v = acc[mi][ni][j] + bv;
                if constexpr (EPI == 0) {
                    int three = (col >= 1536) ? 2 : (col >= 768 ? 1 : 0);
                    int rem = col - three * 768;
                    int h = rem >> 6, d = rem & 63;
                    int b = row >> 11, nn = row & 2047;
                    size_t dst = ((size_t)(b * HEADS + h) * BN + nn) * HD + d;
                    if (three == 0)      Qb[dst] = f2bf(v * 0.125f);
                    else if (three == 1) Kb[dst] = f2bf(v);
                    else                 Vb[dst] = f2bf(v);
                } else {
                    Out[(size_t)row * N + col] = v;
                }
            }
        }
    }
}

// ---------------- flash attention ----------------
// grid (N/64, BH), 256 threads (4 waves x 16 q-rows). KVBLK=64.
// Swapped QK^T: st = mfma(K_tile, Q) -> lane holds S[q=lane&15][16 k's].
__global__ __launch_bounds__(256) void attn_kernel(
    const u16* __restrict__ Qb, const u16* __restrict__ Kb,
    const u16* __restrict__ Vt, u16* __restrict__ Ao) {
    __shared__ u16 Ks[64 * 64];
    __shared__ u16 Vs[64 * 64];
    __shared__ u16 Ps[4][16 * 64];
    int tid = threadIdx.x, wid = tid >> 6, lane = tid & 63, lr = lane & 15, lhi = lane >> 4;
    int bh = blockIdx.y;
    int q0 = blockIdx.x * 64;

    const u16* Qrow = Qb + ((size_t)bh * BN + q0 + wid * 16 + lr) * HD;
    bf16x8 qf0 = *(const bf16x8*)(Qrow + lhi * 8);
    bf16x8 qf1 = *(const bf16x8*)(Qrow + 32 + lhi * 8);

    f32x4 po[4];
#pragma unroll
    for (int i = 0; i < 4; ++i) po[i] = f32x4{0.f, 0.f, 0.f, 0.f};
    float mrun = -1e30f, lrun = 0.f;

    const u16* Kbase = Kb + (size_t)bh * BN * HD;
    const u16* Vbase = Vt + (size_t)bh * HD * BN;

    for (int t = 0; t < BN; t += 64) {
#pragma unroll
        for (int it = 0; it < 2; ++it) {
            int idx = tid + it * 256;
            int row = idx >> 3, ch = idx & 7;
            u32x4 kv = *(const u32x4*)(Kbase + (size_t)(t + row) * HD + ch * 8);
            *(u32x4*)(Ks + row * 64 + ((ch ^ (row & 7)) * 8)) = kv;
            u32x4 vv = *(const u32x4*)(Vbase + (size_t)row * BN + t + ch * 8);
            *(u32x4*)(Vs + row * 64 + ((ch ^ (row & 7)) * 8)) = vv;
        }
        __syncthreads();

        f32x4 st[4];
#pragma unroll
        for (int kg = 0; kg < 4; ++kg) {
            int r = kg * 16 + lr;
            bf16x8 kf0 = *(const bf16x8*)(Ks + r * 64 + ((lhi ^ (r & 7)) * 8));
            bf16x8 kf1 = *(const bf16x8*)(Ks + r * 64 + (((4 + lhi) ^ (r & 7)) * 8));
            f32x4 z = f32x4{0.f, 0.f, 0.f, 0.f};
            z = MFMA16(kf0, qf0, z);
            st[kg] = MFMA16(kf1, qf1, z);
        }

        float mt = -1e30f;
#pragma unroll
        for (int kg = 0; kg < 4; ++kg)
#pragma unroll
            for (int j = 0; j < 4; ++j) mt = fmaxf(mt, st[kg][j]);
        mt = fmaxf(mt, __shfl_xor(mt, 16));
        mt = fmaxf(mt, __shfl_xor(mt, 32));
        float mnew = fmaxf(mrun, mt);
        float resc = __expf(mrun - mnew);

        float p[4][4];
        float ssum = 0.f;
#pragma unroll
        for (int kg = 0; kg < 4; ++kg)
#pragma unroll
            for (int j = 0; j < 4; ++j) {
                float e = __expf(st[kg][j] - mnew);
                p[kg][j] = e;
                ssum += e;
            }
        ssum += __shfl_xor(ssum, 16);
        ssum += __shfl_xor(ssum, 32);
        lrun = lrun * resc + ssum;
        mrun = mnew;

#pragma unroll
        for (int j = 0; j < 4; ++j) {
            float rj = __shfl(resc, lhi * 4 + j);
#pragma unroll
            for (int dc = 0; dc < 4; ++dc) po[dc][j] *= rj;
        }

        u16* Pw = Ps[wid];
#pragma unroll
        for (int kg = 0; kg < 4; ++kg) {
            union { u16 h[4]; u32x2_ v; } pk;
            pk.h[0] = f2bf(p[kg][0]); pk.h[1] = f2bf(p[kg][1]);
            pk.h[2] = f2bf(p[kg][2]); pk.h[3] = f2bf(p[kg][3]);
            int elem = lr * 64 + ((kg * 16 + lhi * 4) ^ ((lr & 7) * 8));
            *(u32x2*)(Pw + elem) = pk.v;
        }
        bf16x8 pa0 = *(const bf16x8*)(Pw + lr * 64 + ((lhi * 8) ^ ((lr & 7) * 8)));
        bf16x8 pa1 = *(const bf16x8*)(Pw + lr * 64 + (((32 + lhi * 8)) ^ ((lr & 7) * 8)));

#pragma unroll
        for (int dc = 0; dc < 4; ++dc) {
            int vr = dc * 16 + lr;
            bf16x8 v0 = *(const bf16x8*)(Vs + vr * 64 + ((lhi ^ (vr & 7)) * 8));
            bf16x8 v1 = *(const bf16x8*)(Vs + vr * 64 + (((4 + lhi) ^ (vr & 7)) * 8));
            po[dc] = MFMA16(pa0, v0, po[dc]);
            po[dc] = MFMA16(pa1, v1, po[dc]);
        }
        __syncthreads();
    }

    int b = bh / HEADS, h = bh % HEADS;
    float linv[4];
#pragma unroll
    for (int j = 0; j < 4; ++j) linv[j] = 1.f / __shfl(lrun, lhi * 4 + j);
#pragma unroll
    for (int dc = 0; dc < 4; ++dc)
#pragma unroll
        for (int j = 0; j < 4; ++j) {
            int row = q0 + wid * 16 + lhi * 4 + j;
            size_t dst = ((size_t)(b * BN + row)) * CDIM + h * HD + dc * 16 + lr;
            Ao[dst] = f2bf(po[dc][j] * linv[j]);
        }
}

// ---------------- launch ----------------
extern "C" void kernel_launch(void* const* d_in, const int* in_sizes, int n_in,
                              void* d_out, int out_size, void* d_ws, size_t ws_size,
                              hipStream_t stream) {
    const float* x      = (const float*)d_in[0];
    const float* w_qkv  = (const float*)d_in[1];
    const float* b_qkv  = (const float*)d_in[2];
    const float* w_proj = (const float*)d_in[3];
    const float* b_proj = (const float*)d_in[4];
    float* out = (float*)d_out;

    char* ws = (char*)d_ws;
    const size_t SZ_XBF   = (size_t)MROWS * CDIM * 2;       // 6.0 MB
    const size_t SZ_WQKV  = (size_t)3 * CDIM * CDIM * 2;    // 3.4 MB
    const size_t SZ_WPROJ = (size_t)CDIM * CDIM * 2;        // 1.1 MB
    const size_t SZ_HEADS = (size_t)NBH * BN * HD * 2;      // 6.0 MB

    u16* x_bf    = (u16*)ws; ws += SZ_XBF;
    u16* wqkv_t  = (u16*)ws; ws += SZ_WQKV;
    u16* wproj_t = (u16*)ws; ws += SZ_WPROJ;
    u16* Qb      = (u16*)ws; ws += SZ_HEADS;
    u16* Kb      = (u16*)ws; ws += SZ_HEADS;
    u16* Vb      = (u16*)ws; ws += SZ_HEADS;
    u16* Vt      = (u16*)ws; ws += SZ_HEADS;
    u16* Ao      = (u16*)ws; ws += SZ_XBF;

    // 1) cast x -> bf16
    cast_x_kernel<<<(MROWS * CDIM / 8 + 255) / 256, 256, 0, stream>>>(x, x_bf, MROWS * CDIM / 8);
    // 2) weights -> bf16, transposed to [N][K]
    transpose_to_bf16<float><<<dim3(3 * CDIM / 64, CDIM / 64, 1), 256, 0, stream>>>(
        w_qkv, wqkv_t, CDIM, 3 * CDIM, 0, 0);
    transpose_to_bf16<float><<<dim3(CDIM / 64, CDIM / 64, 1), 256, 0, stream>>>(
        w_proj, wproj_t, CDIM, CDIM, 0, 0);
    // 3) QKV projection + scatter (Q pre-scaled by 1/sqrt(D))
    gemm_bt<0><<<dim3(MROWS / 128, 3 * CDIM / 128), 256, 0, stream>>>(
        x_bf, wqkv_t, b_qkv, MROWS, 3 * CDIM, CDIM, Qb, Kb, Vb, nullptr);
    // 4) V -> V^T per head ([BH][N][D] -> [BH][D][N])
    transpose_to_bf16<u16><<<dim3(1, BN / 64, NBH), 256, 0, stream>>>(
        Vb, Vt, BN, HD, (long long)BN * HD, (long long)HD * BN);
    // 5) flash attention -> Ao [B*N][C] bf16
    attn_kernel<<<dim3(BN / 64, NBH), 256, 0, stream>>>(Qb, Kb, Vt, Ao);
    // 6) output projection (fp32 out + bias)
    gemm_bt<1><<<dim3(MROWS / 128, CDIM / 128), 256, 0, stream>>>(
        Ao, wproj_t, b_proj, MROWS, CDIM, CDIM, nullptr, nullptr, nullptr, out);
}